// Round 6
// baseline (131.775 us; speedup 1.0000x reference)
//
#include <hip/hip_runtime.h>

#define NV 2052
#define KD 512
#define RTOT 2564
#define KTOT 256
#define JTOT 8192

typedef __attribute__((ext_vector_type(8))) short short8v;
typedef __attribute__((ext_vector_type(4))) float f32x4;
typedef unsigned short ushort_t;

// ws float offsets (ws ~252 MB, we use ~23 MB)
#define OFF_AF   0u          // fp32 M1 [512][128]
#define OFF_ABF  65536u      // bf16 A' [2688][256]
#define OFF_BBF  409600u     // bf16 B' [8192][256]
#define OFF_YBF  1458176u    // bf16 Y  [256][8192]
#define OFF_PG   2506752u    // fp32 Gram partials [32][4][128][128]
#define OFF_PM1  4603904u    // fp32 m1 partials [16][512][128]
#define OFF_A    5652480u
#define OFF_X    5668864u
#define OFF_HG   5685248u

#define SREC_OFF 4194304u
#define AAUG_OFF 21004288u

#define GLOAD16(g, l) __builtin_amdgcn_global_load_lds( \
    (const __attribute__((address_space(1))) unsigned int*)(g), \
    (__attribute__((address_space(3))) unsigned int*)(l), 16, 0, 0)

__device__ __forceinline__ float dct_val(int k, int v) {
    if (k == 0) return 1.0f / sqrtf(2052.0f);
    int m = (2 * v + 1) * k;
    int r = m % 8208;                       // exact arg reduction mod 2*pi
    float ang = (float)((double)r * (3.14159265358979323846 / 4104.0));
    return sqrtf(2.0f / 2052.0f) * cosf(ang);
}

__device__ __forceinline__ void bf16split(float x, ushort_t& hi, ushort_t& lo) {
    unsigned xb = __float_as_uint(x);
    hi = (ushort_t)(xb >> 16);
    float r = x - __uint_as_float((unsigned)hi << 16);
    lo = (ushort_t)(__float_as_uint(r) >> 16);
}

__device__ __forceinline__ ushort_t bf16rn(float x) {
    unsigned xb = __float_as_uint(x);
    return (ushort_t)((xb + 0x7fffu + ((xb >> 16) & 1u)) >> 16);
}

// ========== FRONT: blocks 0..1023 = m1 partials; 1024..5119 = hilbert ==========
__global__ __launch_bounds__(256) void k_front(const float* __restrict__ LF, const float* __restrict__ z,
                                               float* __restrict__ Pm1,
                                               ushort_t* __restrict__ Ybf, ushort_t* __restrict__ Bbf) {
    __shared__ float sh[8][132];
    const int tid = threadIdx.x;
    const int bid = blockIdx.x;
    if (bid < 1024) {
        // ---- M1 partials: kg = bid&63 (8 k-rows), vch = bid>>6 ----
        const int t = tid & 127;
        const int kk = tid >> 7;       // 0/1
        const int k0 = (bid & 63) * 8;
        const int vch = bid >> 6;
        const int v0 = vch * 128;
        const int nv = (vch == 15) ? 132 : 128;
        for (int p = tid; p < 1056; p += 256) {
            int rr = p / 132, cc = p - rr * 132;
            sh[rr][cc] = dct_val(k0 + rr, v0 + cc);
        }
        __syncthreads();
        const float* lf = LF + (size_t)v0 * 128 + t;
        float a0 = 0.f, a1 = 0.f, a2 = 0.f, a3 = 0.f;
        for (int vi = 0; vi + 2 <= nv; vi += 2) {
            float l0 = lf[vi * 128], l1 = lf[vi * 128 + 128];
            a0 += sh[kk + 0][vi] * l0; a1 += sh[kk + 2][vi] * l0;
            a2 += sh[kk + 4][vi] * l0; a3 += sh[kk + 6][vi] * l0;
            a0 += sh[kk + 0][vi + 1] * l1; a1 += sh[kk + 2][vi + 1] * l1;
            a2 += sh[kk + 4][vi + 1] * l1; a3 += sh[kk + 6][vi + 1] * l1;
        }
        float* P = Pm1 + (size_t)vch * 65536;
        P[(k0 + kk + 0) * 128 + t] = a0;
        P[(k0 + kk + 2) * 128 + t] = a1;
        P[(k0 + kk + 4) * 128 + t] = a2;
        P[(k0 + kk + 6) * 128 + t] = a3;
    } else {
        // ---- Hilbert: rid = (bid-1024)*2 + rr ----
        const int t = tid & 127;
        const int rr = tid >> 7;
        const int rid = (bid - 1024) * 2 + rr;   // b*128+i
        const int b = rid >> 7, i = rid & 127;
        sh[rr][t] = z[(size_t)rid * 128 + t];
        if (tid < 128) {
            float hv = 0.f;
            if (t & 1) {
                float ang = 3.14159265358979323846f * (float)t * (1.0f / 128.0f);
                hv = (cosf(ang) / sinf(ang)) * (1.0f / 64.0f);
            }
            sh[2][t] = hv;
        }
        __syncthreads();
        float acc = 0.f;
        #pragma unroll 8
        for (int q = 0; q < 64; ++q) {
            int d = 2 * q + 1;
            acc += sh[2][d] * sh[rr][(t - d) & 127];
        }
        float zv = sh[rr][t];
        float inv = rsqrtf(zv * zv + acc * acc);
        Ybf[(size_t)i * JTOT + b * 128 + t] = bf16rn(zv * inv);
        Ybf[(size_t)(128 + i) * JTOT + b * 128 + t] = bf16rn(acc * inv);
        ushort_t hi = (ushort_t)(__float_as_uint(zv) >> 16);
        ushort_t* row = Bbf + (size_t)rid * KTOT;
        row[t] = hi; row[128 + t] = hi;
    }
}

// ---------- reduce partials -> AF fp32 + Abf bf16 (hi,lo) rows 0..511 ----------
__global__ __launch_bounds__(256) void k_m1red(const float* __restrict__ Pm1, float* __restrict__ AF,
                                               ushort_t* __restrict__ Abf) {
    int id = blockIdx.x * 256 + threadIdx.x;  // 65536
    float s = 0.f;
    #pragma unroll
    for (int p = 0; p < 16; ++p) s += Pm1[p * 65536 + id];
    AF[id] = s;
    int rid = id >> 7, t = id & 127;
    ushort_t hi, lo; bf16split(s, hi, lo);
    ushort_t* row = Abf + (size_t)rid * KTOT;
    row[t] = hi; row[128 + t] = lo;
}

// ---------- M2 = dctT @ M1 -> Abf rows 512..2563; 8 v-rows per block ----------
__global__ __launch_bounds__(256) void k_m2(const float* __restrict__ M1, ushort_t* __restrict__ Abf) {
    __shared__ float sd[8][128];
    const int tid = threadIdx.x;
    const int t = tid & 127;
    const int vv = tid >> 7;     // 0/1
    const int v0 = blockIdx.x * 8;
    float a0 = 0.f, a1 = 0.f, a2 = 0.f, a3 = 0.f;
    for (int kc = 0; kc < KD; kc += 128) {
        __syncthreads();
        for (int p = tid; p < 1024; p += 256) {
            int rr = p >> 7, cc = p & 127;
            sd[rr][cc] = dct_val(kc + cc, v0 + rr);
        }
        __syncthreads();
        const float* m1 = M1 + (size_t)kc * 128 + t;
        #pragma unroll 4
        for (int ki = 0; ki < 128; ++ki) {
            float m = m1[ki * 128];
            a0 += sd[vv + 0][ki] * m;
            a1 += sd[vv + 2][ki] * m;
            a2 += sd[vv + 4][ki] * m;
            a3 += sd[vv + 6][ki] * m;
        }
    }
    float vals[4] = {a0, a1, a2, a3};
    #pragma unroll
    for (int q = 0; q < 4; ++q) {
        int myv = v0 + vv + q * 2;
        if (myv < NV) {
            ushort_t hi, lo; bf16split(vals[q], hi, lo);
            ushort_t* row = Abf + (size_t)(KD + myv) * KTOT;
            row[t] = hi; row[128 + t] = lo;
        }
    }
}

// ========== BACK: blocks 0..1343 = big GEMM; 1344..1471 = Gram ==========
__global__ __launch_bounds__(256) void k_back(const ushort_t* __restrict__ Abf, const ushort_t* __restrict__ Bbf,
                                              const ushort_t* __restrict__ Ybf,
                                              float* __restrict__ out, float* __restrict__ Pg) {
    __shared__ float SMf[8704];            // 34816 B
    ushort_t* Al = (ushort_t*)SMf;         // [128 rows][64 k] chunk-swizzled
    ushort_t* Bl = Al + 8192;
    const int tid = threadIdx.x;
    const int wave = tid >> 6;
    const int lane = tid & 63;
    const int wr = wave >> 1, wc = wave & 1;
    const int l15 = lane & 15;
    const int lhi = lane >> 4;
    const int bid = blockIdx.x;

    f32x4 acc[4][4];
    #pragma unroll
    for (int i = 0; i < 4; ++i)
        #pragma unroll
        for (int j = 0; j < 4; ++j)
            acc[i][j] = (f32x4){0.f, 0.f, 0.f, 0.f};

    if (bid < 1344) {
        // ---------- big GEMM ----------
        const int j0 = (bid & 63) * 128;
        const int r0 = (bid >> 6) * 128;
        for (int kc = 0; kc < KTOT; kc += 64) {
            __syncthreads();
            #pragma unroll
            for (int i = 0; i < 4; ++i) {
                int elt = (wave * 4 + i) * 64 + lane;
                int m = elt >> 3;
                int c = elt & 7;
                int sc = c ^ (m & 7);
                const ushort_t* ga = Abf + (size_t)(r0 + m) * KTOT + kc + sc * 8;
                const ushort_t* gb = Bbf + (size_t)(j0 + m) * KTOT + kc + sc * 8;
                GLOAD16(ga, &Al[(wave * 4 + i) * 512]);
                GLOAD16(gb, &Bl[(wave * 4 + i) * 512]);
            }
            asm volatile("s_waitcnt vmcnt(0)" ::: "memory");
            __syncthreads();
            #pragma unroll
            for (int kk = 0; kk < 2; ++kk) {
                short8v av[4], bv[4];
                #pragma unroll
                for (int mi = 0; mi < 4; ++mi) {
                    int m = wr * 64 + mi * 16 + l15;
                    int ch = (kk * 4 + lhi) ^ (m & 7);
                    av[mi] = *(const short8v*)&Al[m * 64 + ch * 8];
                }
                #pragma unroll
                for (int ni = 0; ni < 4; ++ni) {
                    int n = wc * 64 + ni * 16 + l15;
                    int ch = (kk * 4 + lhi) ^ (n & 7);
                    bv[ni] = *(const short8v*)&Bl[n * 64 + ch * 8];
                }
                #pragma unroll
                for (int mi = 0; mi < 4; ++mi)
                    #pragma unroll
                    for (int ni = 0; ni < 4; ++ni)
                        acc[mi][ni] = __builtin_amdgcn_mfma_f32_16x16x32_bf16(av[mi], bv[ni], acc[mi][ni], 0, 0, 0);
            }
        }
        // epilogue: LDS transpose -> coalesced float4 stores
        const unsigned bb = (unsigned)(bid & 63);
        #pragma unroll
        for (int hhalf = 0; hhalf < 2; ++hhalf) {
            __syncthreads();
            if (wc == hhalf) {
                #pragma unroll
                for (int mi = 0; mi < 4; ++mi)
                    #pragma unroll
                    for (int ni = 0; ni < 4; ++ni)
                        #pragma unroll
                        for (int reg = 0; reg < 4; ++reg) {
                            int rl = wr * 64 + mi * 16 + lhi * 4 + reg;
                            int cl = ni * 16 + l15;
                            SMf[rl * 68 + cl] = acc[mi][ni][reg];
                        }
            }
            __syncthreads();
            int rl = tid >> 1;
            int cs = (tid & 1) * 32;
            int r = r0 + rl;
            if (r < RTOT) {
                unsigned base;
                if (r < KD) base = bb * 65536u + (unsigned)r * 128u;
                else        base = SREC_OFF + bb * 262656u + (unsigned)(r - KD) * 128u;
                base += hhalf * 64 + cs;
                const float* src = &SMf[rl * 68 + cs];
                float* dst = out + base;
                #pragma unroll
                for (int q = 0; q < 8; ++q)
                    *(float4*)(dst + q * 4) = *(const float4*)(src + q * 4);
            }
        }
    } else {
        // ---------- Gram partials ----------
        const int g = bid - 1344;
        const int j0 = (g & 1) * 128;
        const int i0 = ((g >> 1) & 1) * 128;
        const int sk = g >> 2;
        const int kc0 = sk * 256;
        for (int kc = kc0; kc < kc0 + 256; kc += 64) {
            __syncthreads();
            #pragma unroll
            for (int i = 0; i < 4; ++i) {
                int elt = (wave * 4 + i) * 64 + lane;
                int m = elt >> 3;
                int c = elt & 7;
                int sc = c ^ (m & 7);
                const ushort_t* ga = Ybf + (size_t)(i0 + m) * JTOT + kc + sc * 8;
                const ushort_t* gb = Ybf + (size_t)(j0 + m) * JTOT + kc + sc * 8;
                GLOAD16(ga, &Al[(wave * 4 + i) * 512]);
                GLOAD16(gb, &Bl[(wave * 4 + i) * 512]);
            }
            asm volatile("s_waitcnt vmcnt(0)" ::: "memory");
            __syncthreads();
            #pragma unroll
            for (int kk = 0; kk < 2; ++kk) {
                short8v av[4], bv[4];
                #pragma unroll
                for (int mi = 0; mi < 4; ++mi) {
                    int m = wr * 64 + mi * 16 + l15;
                    int ch = (kk * 4 + lhi) ^ (m & 7);
                    av[mi] = *(const short8v*)&Al[m * 64 + ch * 8];
                }
                #pragma unroll
                for (int ni = 0; ni < 4; ++ni) {
                    int n = wc * 64 + ni * 16 + l15;
                    int ch = (kk * 4 + lhi) ^ (n & 7);
                    bv[ni] = *(const short8v*)&Bl[n * 64 + ch * 8];
                }
                #pragma unroll
                for (int mi = 0; mi < 4; ++mi)
                    #pragma unroll
                    for (int ni = 0; ni < 4; ++ni)
                        acc[mi][ni] = __builtin_amdgcn_mfma_f32_16x16x32_bf16(av[mi], bv[ni], acc[mi][ni], 0, 0, 0);
            }
        }
        const int q = ((g >> 1) & 1) * 2 + (g & 1);
        float* P = Pg + (size_t)(sk * 4 + q) * 16384;
        #pragma unroll
        for (int mi = 0; mi < 4; ++mi)
            #pragma unroll
            for (int reg = 0; reg < 4; ++reg) {
                int rl = wr * 64 + mi * 16 + lhi * 4 + reg;
                #pragma unroll
                for (int ni = 0; ni < 4; ++ni) {
                    int cl = wc * 64 + ni * 16 + l15;
                    P[rl * 128 + cl] = acc[mi][ni][reg];
                }
            }
    }
}

// ---------- combine Gram partials -> plv -> a; x = mean_b z ----------
__global__ __launch_bounds__(256) void k_plvx(const float* __restrict__ Pg, const float* __restrict__ z,
                                              float* __restrict__ A, float* __restrict__ X) {
    int id = blockIdx.x * 256 + threadIdx.x;  // 16384
    float R = 0.f, I = 0.f;
    #pragma unroll 8
    for (int sk = 0; sk < 32; ++sk) {
        const float* P = Pg + (size_t)sk * 65536 + id;
        R += P[0] + P[3 * 16384];
        I += P[2 * 16384] - P[1 * 16384];
    }
    float plv = sqrtf(R * R + I * I) * (1.0f / 8192.0f);
    A[id] = (plv >= 0.5f) ? 1.0f : 0.0f;
    float s = 0.f;
    for (int b = 0; b < 64; ++b) s += z[(size_t)b * 16384 + id];
    X[id] = s * (1.0f / 64.0f);
}

// ---------- fused ax + hg: block = 2 full i-rows ----------
__global__ __launch_bounds__(256) void k_axhg(const float* __restrict__ A, const float* __restrict__ X,
                                              const float* __restrict__ Wg, const float* __restrict__ bg,
                                              float* __restrict__ HG) {
    __shared__ float sAX[2][128];
    const int tid = threadIdx.x;
    const int t = tid & 127;
    const int ii = tid >> 7;
    const int i = blockIdx.x * 2 + ii;
    float s = 0.f;
    const float* arow = A + (size_t)i * 128;
    #pragma unroll 4
    for (int j = 0; j < 128; ++j) s += arow[j] * X[j * 128 + t];
    sAX[ii][t] = s;
    __syncthreads();
    if (tid < 128) {
        int i2 = tid >> 6;           // 0/1
        int h = tid & 63;
        float v = bg[h];
        #pragma unroll 4
        for (int t2 = 0; t2 < 128; ++t2) v += sAX[i2][t2] * Wg[t2 * 64 + h];
        HG[(size_t)(blockIdx.x * 2 + i2) * 64 + h] = fmaxf(v, 0.f);
    }
}

// ---------- a_aug ----------
__global__ __launch_bounds__(256) void k_aaug(const float* __restrict__ HG, const float* __restrict__ A,
                                              const float* __restrict__ U, float* __restrict__ out) {
    int id = blockIdx.x * 256 + threadIdx.x;  // 16384
    int i = id >> 7, j = id & 127;
    float dot = 0.f;
    #pragma unroll 8
    for (int h = 0; h < 64; ++h) dot += HG[i * 64 + h] * HG[j * 64 + h];
    float p = 1.f / (1.f + expf(-dot));
    float e = 0.5f * p + 0.5f * A[id];
    float gmb = -logf(-logf(U[id]));
    float arg = (logf(e) - logf(1.f - e) + gmb) * 10.0f;
    out[AAUG_OFF + id] = 1.f / (1.f + expf(-arg));
}

extern "C" void kernel_launch(void* const* d_in, const int* in_sizes, int n_in,
                              void* d_out, int out_size, void* d_ws, size_t ws_size,
                              hipStream_t stream) {
    const float* z  = (const float*)d_in[0];
    const float* LF = (const float*)d_in[1];
    const float* U  = (const float*)d_in[2];
    const float* Wg = (const float*)d_in[3];
    const float* bg = (const float*)d_in[4];
    float* out = (float*)d_out;
    float* W = (float*)d_ws;

    float* AF  = W + OFF_AF;
    ushort_t* Abf = (ushort_t*)(W + OFF_ABF);
    ushort_t* Bbf = (ushort_t*)(W + OFF_BBF);
    ushort_t* Ybf = (ushort_t*)(W + OFF_YBF);
    float* Pg  = W + OFF_PG;
    float* Pm1 = W + OFF_PM1;
    float* A   = W + OFF_A;
    float* X   = W + OFF_X;
    float* HG  = W + OFF_HG;

    k_front<<<5120, 256, 0, stream>>>(LF, z, Pm1, Ybf, Bbf);
    k_m1red<<<256, 256, 0, stream>>>(Pm1, AF, Abf);
    k_m2   <<<257, 256, 0, stream>>>(AF, Abf);
    k_back <<<1472, 256, 0, stream>>>(Abf, Bbf, Ybf, out, Pg);
    k_plvx <<<64, 256, 0, stream>>>(Pg, z, A, X);
    k_axhg <<<64, 256, 0, stream>>>(A, X, Wg, bg, HG);
    k_aaug <<<64, 256, 0, stream>>>(HG, A, U, out);
}

// Round 7
// 124.191 us; speedup vs baseline: 1.0611x; 1.0611x over previous
//
#include <hip/hip_runtime.h>

#define NV 2052
#define KD 512
#define RTOT 2564
#define KTOT 256
#define JTOT 8192

typedef __attribute__((ext_vector_type(8))) short short8v;
typedef __attribute__((ext_vector_type(4))) float f32x4;
typedef unsigned short ushort_t;

// ws float offsets
#define OFF_AF   0u          // fp32 M1 [512][128]
#define OFF_ABF  65536u      // bf16 A' [2688][256]
#define OFF_BBF  409600u     // bf16 B' [8192][256]
#define OFF_YBF  1458176u    // bf16 Y  [256][8192]
#define OFF_PG   2506752u    // fp32 Gram partials [32][4][128][128]
#define OFF_PM1  4603904u    // fp32 m1 partials [16][512][128]
#define OFF_A    5652480u
#define OFF_X    5668864u
#define OFF_HG   5685248u

#define SREC_OFF 4194304u
#define AAUG_OFF 21004288u

#define GLOAD16(g, l) __builtin_amdgcn_global_load_lds( \
    (const __attribute__((address_space(1))) unsigned int*)(g), \
    (__attribute__((address_space(3))) unsigned int*)(l), 16, 0, 0)

__device__ __forceinline__ float dct_val(int k, int v) {
    if (k == 0) return 1.0f / sqrtf(2052.0f);
    int m = (2 * v + 1) * k;
    int r = m % 8208;                       // exact arg reduction mod 2*pi
    float ang = (float)((double)r * (3.14159265358979323846 / 4104.0));
    return sqrtf(2.0f / 2052.0f) * cosf(ang);
}

__device__ __forceinline__ void bf16split(float x, ushort_t& hi, ushort_t& lo) {
    unsigned xb = __float_as_uint(x);
    hi = (ushort_t)(xb >> 16);
    float r = x - __uint_as_float((unsigned)hi << 16);
    lo = (ushort_t)(__float_as_uint(r) >> 16);
}

__device__ __forceinline__ ushort_t bf16rn(float x) {
    unsigned xb = __float_as_uint(x);
    return (ushort_t)((xb + 0x7fffu + ((xb >> 16) & 1u)) >> 16);
}

// ---------- M1 partials: grid (64 k-groups, 16 v-chunks) ----------
__global__ __launch_bounds__(256) void k_m1(const float* __restrict__ LF, float* __restrict__ Pm1) {
    __shared__ float sd[8][132];
    const int tid = threadIdx.x;
    const int t = tid & 127;
    const int kk = tid >> 7;       // 0/1
    const int k0 = blockIdx.x * 8;
    const int vch = blockIdx.y;
    const int v0 = vch * 128;
    const int nv = (vch == 15) ? 132 : 128;
    for (int p = tid; p < 1056; p += 256) {
        int rr = p / 132, cc = p - rr * 132;
        sd[rr][cc] = dct_val(k0 + rr, v0 + cc);
    }
    __syncthreads();
    const float* lf = LF + (size_t)v0 * 128 + t;
    float a0 = 0.f, a1 = 0.f, a2 = 0.f, a3 = 0.f;
    for (int vi = 0; vi + 2 <= nv; vi += 2) {
        float l0 = lf[vi * 128], l1 = lf[vi * 128 + 128];
        a0 += sd[kk + 0][vi] * l0; a1 += sd[kk + 2][vi] * l0;
        a2 += sd[kk + 4][vi] * l0; a3 += sd[kk + 6][vi] * l0;
        a0 += sd[kk + 0][vi + 1] * l1; a1 += sd[kk + 2][vi + 1] * l1;
        a2 += sd[kk + 4][vi + 1] * l1; a3 += sd[kk + 6][vi + 1] * l1;
    }
    float* P = Pm1 + (size_t)vch * 65536;
    P[(k0 + kk + 0) * 128 + t] = a0;
    P[(k0 + kk + 2) * 128 + t] = a1;
    P[(k0 + kk + 4) * 128 + t] = a2;
    P[(k0 + kk + 6) * 128 + t] = a3;
}

// ---------- Hilbert: emit Y bf16 AND B' bf16 (hi,hi) rows ----------
__global__ __launch_bounds__(256) void k_hilb(const float* __restrict__ z,
                                              ushort_t* __restrict__ Ybf, ushort_t* __restrict__ Bbf) {
    __shared__ float zr[2][128];
    __shared__ float h[128];
    const int tid = threadIdx.x;
    const int t = tid & 127;
    const int rr = tid >> 7;
    const int rid = blockIdx.x * 2 + rr;   // b*128+i
    const int b = rid >> 7, i = rid & 127;
    zr[rr][t] = z[(size_t)rid * 128 + t];
    if (tid < 128) {
        float hv = 0.f;
        if (t & 1) {
            float ang = 3.14159265358979323846f * (float)t * (1.0f / 128.0f);
            hv = (cosf(ang) / sinf(ang)) * (1.0f / 64.0f);
        }
        h[t] = hv;
    }
    __syncthreads();
    float acc = 0.f;
    #pragma unroll 8
    for (int q = 0; q < 64; ++q) {
        int d = 2 * q + 1;
        acc += h[d] * zr[rr][(t - d) & 127];
    }
    float zv = zr[rr][t];
    float inv = rsqrtf(zv * zv + acc * acc);
    Ybf[(size_t)i * JTOT + b * 128 + t] = bf16rn(zv * inv);
    Ybf[(size_t)(128 + i) * JTOT + b * 128 + t] = bf16rn(acc * inv);
    ushort_t hi = (ushort_t)(__float_as_uint(zv) >> 16);
    ushort_t* row = Bbf + (size_t)rid * KTOT;
    row[t] = hi; row[128 + t] = hi;
}

// ---------- reduce partials -> AF fp32 + Abf bf16 (hi,lo) rows 0..511 ----------
__global__ __launch_bounds__(256) void k_m1red(const float* __restrict__ Pm1, float* __restrict__ AF,
                                               ushort_t* __restrict__ Abf) {
    int id = blockIdx.x * 256 + threadIdx.x;  // 65536
    float s = 0.f;
    #pragma unroll
    for (int p = 0; p < 16; ++p) s += Pm1[p * 65536 + id];
    AF[id] = s;
    int rid = id >> 7, t = id & 127;
    ushort_t hi, lo; bf16split(s, hi, lo);
    ushort_t* row = Abf + (size_t)rid * KTOT;
    row[t] = hi; row[128 + t] = lo;
}

// ---------- M2 = dctT @ M1 -> Abf rows 512..2563 (R5-proven 1026-block version) ----------
__global__ __launch_bounds__(256) void k_m2(const float* __restrict__ M1, ushort_t* __restrict__ Abf) {
    __shared__ float sd[2][128];
    const int tid = threadIdx.x;
    const int t = tid & 127;
    const int vv = tid >> 7;
    const int myv = blockIdx.x * 2 + vv;
    float a0 = 0.f, a1 = 0.f, a2 = 0.f, a3 = 0.f;
    for (int kc = 0; kc < KD; kc += 128) {
        __syncthreads();
        sd[vv][t] = dct_val(kc + t, myv);
        __syncthreads();
        const float* m1 = M1 + (size_t)kc * 128 + t;
        #pragma unroll 8
        for (int ki = 0; ki < 32; ++ki) {
            a0 += sd[vv][ki +  0] * m1[(ki +  0) * 128];
            a1 += sd[vv][ki + 32] * m1[(ki + 32) * 128];
            a2 += sd[vv][ki + 64] * m1[(ki + 64) * 128];
            a3 += sd[vv][ki + 96] * m1[(ki + 96) * 128];
        }
    }
    float s = (a0 + a1) + (a2 + a3);
    ushort_t hi, lo; bf16split(s, hi, lo);
    ushort_t* row = Abf + (size_t)(KD + myv) * KTOT;
    row[t] = hi; row[128 + t] = lo;
}

// ---------- MFMA GEMM, 2-phase double-buffered ----------
__global__ __launch_bounds__(256) void k_gemm(const ushort_t* __restrict__ Abf, const ushort_t* __restrict__ Bbf,
                                              float* __restrict__ out) {
    __shared__ ushort_t SM[2][16384];      // 64 KB: per buf, Al[0..8191] Bl[8192..16383]
    const int tid = threadIdx.x;
    const int wave = tid >> 6;
    const int lane = tid & 63;
    const int j0 = blockIdx.x * 128;
    const int r0 = blockIdx.y * 128;
    const int wr = wave >> 1, wc = wave & 1;
    const int l15 = lane & 15;
    const int lhi = lane >> 4;

    f32x4 acc[4][4];
    #pragma unroll
    for (int i = 0; i < 4; ++i)
        #pragma unroll
        for (int j = 0; j < 4; ++j)
            acc[i][j] = (f32x4){0.f, 0.f, 0.f, 0.f};

    auto stage = [&](int buf, int kc) {
        #pragma unroll
        for (int i = 0; i < 4; ++i) {
            int elt = (wave * 4 + i) * 64 + lane;
            int m = elt >> 3;
            int sc = (elt & 7) ^ (m & 7);
            GLOAD16(Abf + (size_t)(r0 + m) * KTOT + kc + sc * 8, &SM[buf][(wave * 4 + i) * 512]);
            GLOAD16(Bbf + (size_t)(j0 + m) * KTOT + kc + sc * 8, &SM[buf][8192 + (wave * 4 + i) * 512]);
        }
    };

    stage(0, 0);
    asm volatile("s_waitcnt vmcnt(0)" ::: "memory");
    __syncthreads();
    #pragma unroll
    for (int t = 0; t < 4; ++t) {
        const int cur = t & 1;
        if (t < 3) stage(cur ^ 1, (t + 1) * 64);   // issue next tile's loads first
        const ushort_t* Al = &SM[cur][0];
        const ushort_t* Bl = &SM[cur][8192];
        #pragma unroll
        for (int kk = 0; kk < 2; ++kk) {
            short8v av[4], bv[4];
            #pragma unroll
            for (int mi = 0; mi < 4; ++mi) {
                int m = wr * 64 + mi * 16 + l15;
                int ch = (kk * 4 + lhi) ^ (m & 7);
                av[mi] = *(const short8v*)&Al[m * 64 + ch * 8];
            }
            #pragma unroll
            for (int ni = 0; ni < 4; ++ni) {
                int n = wc * 64 + ni * 16 + l15;
                int ch = (kk * 4 + lhi) ^ (n & 7);
                bv[ni] = *(const short8v*)&Bl[n * 64 + ch * 8];
            }
            #pragma unroll
            for (int mi = 0; mi < 4; ++mi)
                #pragma unroll
                for (int ni = 0; ni < 4; ++ni)
                    acc[mi][ni] = __builtin_amdgcn_mfma_f32_16x16x32_bf16(av[mi], bv[ni], acc[mi][ni], 0, 0, 0);
        }
        asm volatile("s_waitcnt vmcnt(0)" ::: "memory");
        __syncthreads();
    }

    // epilogue: LDS transpose -> coalesced float4 stores (two 64-col halves)
    float* SMf = (float*)&SM[0][0];
    const unsigned bb = (unsigned)blockIdx.x;
    #pragma unroll
    for (int hhalf = 0; hhalf < 2; ++hhalf) {
        __syncthreads();
        if (wc == hhalf) {
            #pragma unroll
            for (int mi = 0; mi < 4; ++mi)
                #pragma unroll
                for (int ni = 0; ni < 4; ++ni)
                    #pragma unroll
                    for (int reg = 0; reg < 4; ++reg) {
                        int rl = wr * 64 + mi * 16 + lhi * 4 + reg;
                        int cl = ni * 16 + l15;
                        SMf[rl * 68 + cl] = acc[mi][ni][reg];
                    }
        }
        __syncthreads();
        int rl = tid >> 1;
        int cs = (tid & 1) * 32;
        int r = r0 + rl;
        if (r < RTOT) {
            unsigned base;
            if (r < KD) base = bb * 65536u + (unsigned)r * 128u;
            else        base = SREC_OFF + bb * 262656u + (unsigned)(r - KD) * 128u;
            base += hhalf * 64 + cs;
            const float* src = &SMf[rl * 68 + cs];
            float* dst = out + base;
            #pragma unroll
            for (int q = 0; q < 8; ++q)
                *(float4*)(dst + q * 4) = *(const float4*)(src + q * 4);
        }
    }
}

// ---------- Gram via MFMA, 2-phase double-buffered ----------
__global__ __launch_bounds__(256) void k_gram(const ushort_t* __restrict__ Ybf, float* __restrict__ Pg) {
    __shared__ ushort_t SM[2][16384];
    const int tid = threadIdx.x;
    const int wave = tid >> 6;
    const int lane = tid & 63;
    const int j0 = blockIdx.x * 128;
    const int i0 = blockIdx.y * 128;
    const int kc0 = blockIdx.z * 256;
    const int wr = wave >> 1, wc = wave & 1;
    const int l15 = lane & 15;
    const int lhi = lane >> 4;

    f32x4 acc[4][4];
    #pragma unroll
    for (int i = 0; i < 4; ++i)
        #pragma unroll
        for (int j = 0; j < 4; ++j)
            acc[i][j] = (f32x4){0.f, 0.f, 0.f, 0.f};

    auto stage = [&](int buf, int kc) {
        #pragma unroll
        for (int i = 0; i < 4; ++i) {
            int elt = (wave * 4 + i) * 64 + lane;
            int m = elt >> 3;
            int sc = (elt & 7) ^ (m & 7);
            GLOAD16(Ybf + (size_t)(i0 + m) * JTOT + kc + sc * 8, &SM[buf][(wave * 4 + i) * 512]);
            GLOAD16(Ybf + (size_t)(j0 + m) * JTOT + kc + sc * 8, &SM[buf][8192 + (wave * 4 + i) * 512]);
        }
    };

    stage(0, kc0);
    asm volatile("s_waitcnt vmcnt(0)" ::: "memory");
    __syncthreads();
    #pragma unroll
    for (int t = 0; t < 4; ++t) {
        const int cur = t & 1;
        if (t < 3) stage(cur ^ 1, kc0 + (t + 1) * 64);
        const ushort_t* Al = &SM[cur][0];
        const ushort_t* Bl = &SM[cur][8192];
        #pragma unroll
        for (int kk = 0; kk < 2; ++kk) {
            short8v av[4], bv[4];
            #pragma unroll
            for (int mi = 0; mi < 4; ++mi) {
                int m = wr * 64 + mi * 16 + l15;
                int ch = (kk * 4 + lhi) ^ (m & 7);
                av[mi] = *(const short8v*)&Al[m * 64 + ch * 8];
            }
            #pragma unroll
            for (int ni = 0; ni < 4; ++ni) {
                int n = wc * 64 + ni * 16 + l15;
                int ch = (kk * 4 + lhi) ^ (n & 7);
                bv[ni] = *(const short8v*)&Bl[n * 64 + ch * 8];
            }
            #pragma unroll
            for (int mi = 0; mi < 4; ++mi)
                #pragma unroll
                for (int ni = 0; ni < 4; ++ni)
                    acc[mi][ni] = __builtin_amdgcn_mfma_f32_16x16x32_bf16(av[mi], bv[ni], acc[mi][ni], 0, 0, 0);
        }
        asm volatile("s_waitcnt vmcnt(0)" ::: "memory");
        __syncthreads();
    }

    const int q = blockIdx.y * 2 + blockIdx.x;
    float* P = Pg + (size_t)(blockIdx.z * 4 + q) * 16384;
    #pragma unroll
    for (int mi = 0; mi < 4; ++mi)
        #pragma unroll
        for (int reg = 0; reg < 4; ++reg) {
            int rl = wr * 64 + mi * 16 + lhi * 4 + reg;
            #pragma unroll
            for (int ni = 0; ni < 4; ++ni) {
                int cl = wc * 64 + ni * 16 + l15;
                P[rl * 128 + cl] = acc[mi][ni][reg];
            }
        }
}

// ---------- combine Gram partials -> plv -> a; x = mean_b z ----------
__global__ __launch_bounds__(256) void k_plvx(const float* __restrict__ Pg, const float* __restrict__ z,
                                              float* __restrict__ A, float* __restrict__ X) {
    int id = blockIdx.x * 256 + threadIdx.x;  // 16384
    float R = 0.f, I = 0.f;
    #pragma unroll 8
    for (int sk = 0; sk < 32; ++sk) {
        const float* P = Pg + (size_t)sk * 65536 + id;
        R += P[0] + P[3 * 16384];
        I += P[2 * 16384] - P[1 * 16384];
    }
    float plv = sqrtf(R * R + I * I) * (1.0f / 8192.0f);
    A[id] = (plv >= 0.5f) ? 1.0f : 0.0f;
    float s = 0.f;
    for (int b = 0; b < 64; ++b) s += z[(size_t)b * 16384 + id];
    X[id] = s * (1.0f / 64.0f);
}

// ---------- fused ax + hg ----------
__global__ __launch_bounds__(256) void k_axhg(const float* __restrict__ A, const float* __restrict__ X,
                                              const float* __restrict__ Wg, const float* __restrict__ bg,
                                              float* __restrict__ HG) {
    __shared__ float sAX[2][128];
    const int tid = threadIdx.x;
    const int t = tid & 127;
    const int ii = tid >> 7;
    const int i = blockIdx.x * 2 + ii;
    float s = 0.f;
    const float* arow = A + (size_t)i * 128;
    #pragma unroll 4
    for (int j = 0; j < 128; ++j) s += arow[j] * X[j * 128 + t];
    sAX[ii][t] = s;
    __syncthreads();
    if (tid < 128) {
        int i2 = tid >> 6;
        int h = tid & 63;
        float v = bg[h];
        #pragma unroll 4
        for (int t2 = 0; t2 < 128; ++t2) v += sAX[i2][t2] * Wg[t2 * 64 + h];
        HG[(size_t)(blockIdx.x * 2 + i2) * 64 + h] = fmaxf(v, 0.f);
    }
}

// ---------- a_aug ----------
__global__ __launch_bounds__(256) void k_aaug(const float* __restrict__ HG, const float* __restrict__ A,
                                              const float* __restrict__ U, float* __restrict__ out) {
    int id = blockIdx.x * 256 + threadIdx.x;  // 16384
    int i = id >> 7, j = id & 127;
    float dot = 0.f;
    #pragma unroll 8
    for (int h = 0; h < 64; ++h) dot += HG[i * 64 + h] * HG[j * 64 + h];
    float p = 1.f / (1.f + expf(-dot));
    float e = 0.5f * p + 0.5f * A[id];
    float gmb = -logf(-logf(U[id]));
    float arg = (logf(e) - logf(1.f - e) + gmb) * 10.0f;
    out[AAUG_OFF + id] = 1.f / (1.f + expf(-arg));
}

extern "C" void kernel_launch(void* const* d_in, const int* in_sizes, int n_in,
                              void* d_out, int out_size, void* d_ws, size_t ws_size,
                              hipStream_t stream) {
    const float* z  = (const float*)d_in[0];
    const float* LF = (const float*)d_in[1];
    const float* U  = (const float*)d_in[2];
    const float* Wg = (const float*)d_in[3];
    const float* bg = (const float*)d_in[4];
    float* out = (float*)d_out;
    float* W = (float*)d_ws;

    float* AF  = W + OFF_AF;
    ushort_t* Abf = (ushort_t*)(W + OFF_ABF);
    ushort_t* Bbf = (ushort_t*)(W + OFF_BBF);
    ushort_t* Ybf = (ushort_t*)(W + OFF_YBF);
    float* Pg  = W + OFF_PG;
    float* Pm1 = W + OFF_PM1;
    float* A   = W + OFF_A;
    float* X   = W + OFF_X;
    float* HG  = W + OFF_HG;

    k_m1   <<<dim3(64, 16), 256, 0, stream>>>(LF, Pm1);
    k_hilb <<<4096, 256, 0, stream>>>(z, Ybf, Bbf);
    k_m1red<<<256, 256, 0, stream>>>(Pm1, AF, Abf);
    k_m2   <<<1026, 256, 0, stream>>>(AF, Abf);
    k_gemm <<<dim3(64, 21), 256, 0, stream>>>(Abf, Bbf, out);
    k_gram <<<dim3(2, 2, 32), 256, 0, stream>>>(Ybf, Pg);
    k_plvx <<<64, 256, 0, stream>>>(Pg, z, A, X);
    k_axhg <<<64, 256, 0, stream>>>(A, X, Wg, bg, HG);
    k_aaug <<<64, 256, 0, stream>>>(HG, A, U, out);
}

// Round 8
// 119.255 us; speedup vs baseline: 1.1050x; 1.0414x over previous
//
#include <hip/hip_runtime.h>

#define NV 2052
#define KD 512
#define RTOT 2564
#define KTOT 256
#define JTOT 8192

typedef __attribute__((ext_vector_type(8))) short short8v;
typedef __attribute__((ext_vector_type(4))) float f32x4;
typedef unsigned short ushort_t;

// ws float offsets
#define OFF_AF   0u          // fp32 M1 [512][128]
#define OFF_ABF  65536u      // bf16 A' [2688][256]
#define OFF_BBF  409600u     // bf16 B' [8192][256]
#define OFF_YBF  1458176u    // bf16 Y  [256][8192]
#define OFF_PG   2506752u    // fp32 Gram partials [64][4][128][128]
#define OFF_PM1  6701056u    // fp32 m1 partials [16][512][128]
#define OFF_A    7749632u
#define OFF_X    7766016u
#define OFF_HG   7782400u

#define SREC_OFF 4194304u
#define AAUG_OFF 21004288u

#define GLOAD16(g, l) __builtin_amdgcn_global_load_lds( \
    (const __attribute__((address_space(1))) unsigned int*)(g), \
    (__attribute__((address_space(3))) unsigned int*)(l), 16, 0, 0)

__device__ __forceinline__ float dct_val(int k, int v) {
    if (k == 0) return 1.0f / sqrtf(2052.0f);
    int m = (2 * v + 1) * k;
    int r = m % 8208;                       // exact arg reduction mod 2*pi
    float ang = (float)((double)r * (3.14159265358979323846 / 4104.0));
    return sqrtf(2.0f / 2052.0f) * cosf(ang);
}

__device__ __forceinline__ void bf16split(float x, ushort_t& hi, ushort_t& lo) {
    unsigned xb = __float_as_uint(x);
    hi = (ushort_t)(xb >> 16);
    float r = x - __uint_as_float((unsigned)hi << 16);
    lo = (ushort_t)(__float_as_uint(r) >> 16);
}

__device__ __forceinline__ ushort_t bf16rn(float x) {
    unsigned xb = __float_as_uint(x);
    return (ushort_t)((xb + 0x7fffu + ((xb >> 16) & 1u)) >> 16);
}

// ========== FRONT: blocks 0..1023 = m1 partials; 1024..5119 = hilbert ==========
__global__ __launch_bounds__(256) void k_front(const float* __restrict__ LF, const float* __restrict__ z,
                                               float* __restrict__ Pm1,
                                               ushort_t* __restrict__ Ybf, ushort_t* __restrict__ Bbf) {
    __shared__ float sh[8][132];
    const int tid = threadIdx.x;
    const int bid = blockIdx.x;
    if (bid < 1024) {
        // ---- M1 partials: kg = bid&63 (8 k-rows), vch = bid>>6 ----
        const int t = tid & 127;
        const int kk = tid >> 7;       // 0/1
        const int k0 = (bid & 63) * 8;
        const int vch = bid >> 6;
        const int v0 = vch * 128;
        const int nv = (vch == 15) ? 132 : 128;
        for (int p = tid; p < 1056; p += 256) {
            int rr = p / 132, cc = p - rr * 132;
            sh[rr][cc] = dct_val(k0 + rr, v0 + cc);
        }
        __syncthreads();
        const float* lf = LF + (size_t)v0 * 128 + t;
        float a0 = 0.f, a1 = 0.f, a2 = 0.f, a3 = 0.f;
        for (int vi = 0; vi + 2 <= nv; vi += 2) {
            float l0 = lf[vi * 128], l1 = lf[vi * 128 + 128];
            a0 += sh[kk + 0][vi] * l0; a1 += sh[kk + 2][vi] * l0;
            a2 += sh[kk + 4][vi] * l0; a3 += sh[kk + 6][vi] * l0;
            a0 += sh[kk + 0][vi + 1] * l1; a1 += sh[kk + 2][vi + 1] * l1;
            a2 += sh[kk + 4][vi + 1] * l1; a3 += sh[kk + 6][vi + 1] * l1;
        }
        float* P = Pm1 + (size_t)vch * 65536;
        P[(k0 + kk + 0) * 128 + t] = a0;
        P[(k0 + kk + 2) * 128 + t] = a1;
        P[(k0 + kk + 4) * 128 + t] = a2;
        P[(k0 + kk + 6) * 128 + t] = a3;
    } else {
        // ---- Hilbert: rid = (bid-1024)*2 + rr ----
        const int t = tid & 127;
        const int rr = tid >> 7;
        const int rid = (bid - 1024) * 2 + rr;   // b*128+i
        const int b = rid >> 7, i = rid & 127;
        sh[rr][t] = z[(size_t)rid * 128 + t];
        if (tid < 128) {
            float hv = 0.f;
            if (t & 1) {
                float ang = 3.14159265358979323846f * (float)t * (1.0f / 128.0f);
                hv = (cosf(ang) / sinf(ang)) * (1.0f / 64.0f);
            }
            sh[2][t] = hv;
        }
        __syncthreads();
        float acc = 0.f;
        #pragma unroll 8
        for (int q = 0; q < 64; ++q) {
            int d = 2 * q + 1;
            acc += sh[2][d] * sh[rr][(t - d) & 127];
        }
        float zv = sh[rr][t];
        float inv = rsqrtf(zv * zv + acc * acc);
        Ybf[(size_t)i * JTOT + b * 128 + t] = bf16rn(zv * inv);
        Ybf[(size_t)(128 + i) * JTOT + b * 128 + t] = bf16rn(acc * inv);
        ushort_t hi = (ushort_t)(__float_as_uint(zv) >> 16);
        ushort_t* row = Bbf + (size_t)rid * KTOT;
        row[t] = hi; row[128 + t] = hi;
    }
}

// ---------- reduce partials -> AF fp32 + Abf bf16 (hi,lo) rows 0..511 ----------
__global__ __launch_bounds__(256) void k_m1red(const float* __restrict__ Pm1, float* __restrict__ AF,
                                               ushort_t* __restrict__ Abf) {
    int id = blockIdx.x * 256 + threadIdx.x;  // 65536
    float s = 0.f;
    #pragma unroll
    for (int p = 0; p < 16; ++p) s += Pm1[p * 65536 + id];
    AF[id] = s;
    int rid = id >> 7, t = id & 127;
    ushort_t hi, lo; bf16split(s, hi, lo);
    ushort_t* row = Abf + (size_t)rid * KTOT;
    row[t] = hi; row[128 + t] = lo;
}

// ---------- M2 = dctT @ M1 -> Abf rows 512..2563 (proven 1026-block shape) ----------
__global__ __launch_bounds__(256) void k_m2(const float* __restrict__ M1, ushort_t* __restrict__ Abf) {
    __shared__ float sd[2][128];
    const int tid = threadIdx.x;
    const int t = tid & 127;
    const int vv = tid >> 7;
    const int myv = blockIdx.x * 2 + vv;
    float a0 = 0.f, a1 = 0.f, a2 = 0.f, a3 = 0.f;
    for (int kc = 0; kc < KD; kc += 128) {
        __syncthreads();
        sd[vv][t] = dct_val(kc + t, myv);
        __syncthreads();
        const float* m1 = M1 + (size_t)kc * 128 + t;
        #pragma unroll 8
        for (int ki = 0; ki < 32; ++ki) {
            a0 += sd[vv][ki +  0] * m1[(ki +  0) * 128];
            a1 += sd[vv][ki + 32] * m1[(ki + 32) * 128];
            a2 += sd[vv][ki + 64] * m1[(ki + 64) * 128];
            a3 += sd[vv][ki + 96] * m1[(ki + 96) * 128];
        }
    }
    float s = (a0 + a1) + (a2 + a3);
    ushort_t hi, lo; bf16split(s, hi, lo);
    ushort_t* row = Abf + (size_t)(KD + myv) * KTOT;
    row[t] = hi; row[128 + t] = lo;
}

// ========== BACK: blocks 0..1343 = big GEMM; 1344..1599 = Gram (64 K-chunks) ==========
__global__ __launch_bounds__(256) void k_back(const ushort_t* __restrict__ Abf, const ushort_t* __restrict__ Bbf,
                                              const ushort_t* __restrict__ Ybf,
                                              float* __restrict__ out, float* __restrict__ Pg) {
    __shared__ float SMf[8704];            // 34816 B; stage region = first 32KB
    ushort_t* Al = (ushort_t*)SMf;         // [128 rows][64 k] chunk-swizzled
    ushort_t* Bl = Al + 8192;
    const int tid = threadIdx.x;
    const int wave = tid >> 6;
    const int lane = tid & 63;
    const int wr = wave >> 1, wc = wave & 1;
    const int l15 = lane & 15;
    const int lhi = lane >> 4;
    const int bid = blockIdx.x;

    f32x4 acc[4][4];
    #pragma unroll
    for (int i = 0; i < 4; ++i)
        #pragma unroll
        for (int j = 0; j < 4; ++j)
            acc[i][j] = (f32x4){0.f, 0.f, 0.f, 0.f};

    if (bid < 1344) {
        // ---------- big GEMM ----------
        const int j0 = (bid & 63) * 128;
        const int r0 = (bid >> 6) * 128;
        for (int kc = 0; kc < KTOT; kc += 64) {
            __syncthreads();
            #pragma unroll
            for (int i = 0; i < 4; ++i) {
                int elt = (wave * 4 + i) * 64 + lane;
                int m = elt >> 3;
                int sc = (elt & 7) ^ (m & 7);
                GLOAD16(Abf + (size_t)(r0 + m) * KTOT + kc + sc * 8, &Al[(wave * 4 + i) * 512]);
                GLOAD16(Bbf + (size_t)(j0 + m) * KTOT + kc + sc * 8, &Bl[(wave * 4 + i) * 512]);
            }
            asm volatile("s_waitcnt vmcnt(0)" ::: "memory");
            __syncthreads();
            #pragma unroll
            for (int kk = 0; kk < 2; ++kk) {
                short8v av[4], bv[4];
                #pragma unroll
                for (int mi = 0; mi < 4; ++mi) {
                    int m = wr * 64 + mi * 16 + l15;
                    int ch = (kk * 4 + lhi) ^ (m & 7);
                    av[mi] = *(const short8v*)&Al[m * 64 + ch * 8];
                }
                #pragma unroll
                for (int ni = 0; ni < 4; ++ni) {
                    int n = wc * 64 + ni * 16 + l15;
                    int ch = (kk * 4 + lhi) ^ (n & 7);
                    bv[ni] = *(const short8v*)&Bl[n * 64 + ch * 8];
                }
                #pragma unroll
                for (int mi = 0; mi < 4; ++mi)
                    #pragma unroll
                    for (int ni = 0; ni < 4; ++ni)
                        acc[mi][ni] = __builtin_amdgcn_mfma_f32_16x16x32_bf16(av[mi], bv[ni], acc[mi][ni], 0, 0, 0);
            }
        }
        // epilogue: LDS transpose -> coalesced float4 stores (two 64-col halves)
        const unsigned bb = (unsigned)(bid & 63);
        #pragma unroll
        for (int hhalf = 0; hhalf < 2; ++hhalf) {
            __syncthreads();
            if (wc == hhalf) {
                #pragma unroll
                for (int mi = 0; mi < 4; ++mi)
                    #pragma unroll
                    for (int ni = 0; ni < 4; ++ni)
                        #pragma unroll
                        for (int reg = 0; reg < 4; ++reg) {
                            int rl = wr * 64 + mi * 16 + lhi * 4 + reg;
                            int cl = ni * 16 + l15;
                            SMf[rl * 68 + cl] = acc[mi][ni][reg];
                        }
            }
            __syncthreads();
            int rl = tid >> 1;
            int cs = (tid & 1) * 32;
            int r = r0 + rl;
            if (r < RTOT) {
                unsigned base;
                if (r < KD) base = bb * 65536u + (unsigned)r * 128u;
                else        base = SREC_OFF + bb * 262656u + (unsigned)(r - KD) * 128u;
                base += hhalf * 64 + cs;
                const float* src = &SMf[rl * 68 + cs];
                float* dst = out + base;
                #pragma unroll
                for (int q = 0; q < 8; ++q)
                    *(float4*)(dst + q * 4) = *(const float4*)(src + q * 4);
            }
        }
    } else {
        // ---------- Gram partials: 256 blocks = 64 K-chunks x 4 quadrants ----------
        const int g = bid - 1344;
        const int j0 = (g & 1) * 128;
        const int i0 = ((g >> 1) & 1) * 128;
        const int sk = g >> 2;               // 0..63
        const int kc0 = sk * 128;
        for (int kc = kc0; kc < kc0 + 128; kc += 64) {
            __syncthreads();
            #pragma unroll
            for (int i = 0; i < 4; ++i) {
                int elt = (wave * 4 + i) * 64 + lane;
                int m = elt >> 3;
                int sc = (elt & 7) ^ (m & 7);
                GLOAD16(Ybf + (size_t)(i0 + m) * JTOT + kc + sc * 8, &Al[(wave * 4 + i) * 512]);
                GLOAD16(Ybf + (size_t)(j0 + m) * JTOT + kc + sc * 8, &Bl[(wave * 4 + i) * 512]);
            }
            asm volatile("s_waitcnt vmcnt(0)" ::: "memory");
            __syncthreads();
            #pragma unroll
            for (int kk = 0; kk < 2; ++kk) {
                short8v av[4], bv[4];
                #pragma unroll
                for (int mi = 0; mi < 4; ++mi) {
                    int m = wr * 64 + mi * 16 + l15;
                    int ch = (kk * 4 + lhi) ^ (m & 7);
                    av[mi] = *(const short8v*)&Al[m * 64 + ch * 8];
                }
                #pragma unroll
                for (int ni = 0; ni < 4; ++ni) {
                    int n = wc * 64 + ni * 16 + l15;
                    int ch = (kk * 4 + lhi) ^ (n & 7);
                    bv[ni] = *(const short8v*)&Bl[n * 64 + ch * 8];
                }
                #pragma unroll
                for (int mi = 0; mi < 4; ++mi)
                    #pragma unroll
                    for (int ni = 0; ni < 4; ++ni)
                        acc[mi][ni] = __builtin_amdgcn_mfma_f32_16x16x32_bf16(av[mi], bv[ni], acc[mi][ni], 0, 0, 0);
            }
        }
        const int q = ((g >> 1) & 1) * 2 + (g & 1);
        float* P = Pg + (size_t)(sk * 4 + q) * 16384;
        #pragma unroll
        for (int mi = 0; mi < 4; ++mi)
            #pragma unroll
            for (int reg = 0; reg < 4; ++reg) {
                int rl = wr * 64 + mi * 16 + lhi * 4 + reg;
                #pragma unroll
                for (int ni = 0; ni < 4; ++ni) {
                    int cl = wc * 64 + ni * 16 + l15;
                    P[rl * 128 + cl] = acc[mi][ni][reg];
                }
            }
    }
}

// ---------- combine Gram partials -> plv -> a; x = mean_b z ----------
__global__ __launch_bounds__(256) void k_plvx(const float* __restrict__ Pg, const float* __restrict__ z,
                                              float* __restrict__ A, float* __restrict__ X) {
    int id = blockIdx.x * 256 + threadIdx.x;  // 16384
    float R = 0.f, I = 0.f;
    #pragma unroll 8
    for (int sk = 0; sk < 64; ++sk) {
        const float* P = Pg + (size_t)sk * 65536 + id;
        R += P[0] + P[3 * 16384];
        I += P[2 * 16384] - P[1 * 16384];
    }
    float plv = sqrtf(R * R + I * I) * (1.0f / 8192.0f);
    A[id] = (plv >= 0.5f) ? 1.0f : 0.0f;
    float s = 0.f;
    for (int b = 0; b < 64; ++b) s += z[(size_t)b * 16384 + id];
    X[id] = s * (1.0f / 64.0f);
}

// ---------- fused ax + hg ----------
__global__ __launch_bounds__(256) void k_axhg(const float* __restrict__ A, const float* __restrict__ X,
                                              const float* __restrict__ Wg, const float* __restrict__ bg,
                                              float* __restrict__ HG) {
    __shared__ float sAX[2][128];
    const int tid = threadIdx.x;
    const int t = tid & 127;
    const int ii = tid >> 7;
    const int i = blockIdx.x * 2 + ii;
    float s = 0.f;
    const float* arow = A + (size_t)i * 128;
    #pragma unroll 4
    for (int j = 0; j < 128; ++j) s += arow[j] * X[j * 128 + t];
    sAX[ii][t] = s;
    __syncthreads();
    if (tid < 128) {
        int i2 = tid >> 6;
        int h = tid & 63;
        float v = bg[h];
        #pragma unroll 4
        for (int t2 = 0; t2 < 128; ++t2) v += sAX[i2][t2] * Wg[t2 * 64 + h];
        HG[(size_t)(blockIdx.x * 2 + i2) * 64 + h] = fmaxf(v, 0.f);
    }
}

// ---------- a_aug ----------
__global__ __launch_bounds__(256) void k_aaug(const float* __restrict__ HG, const float* __restrict__ A,
                                              const float* __restrict__ U, float* __restrict__ out) {
    int id = blockIdx.x * 256 + threadIdx.x;  // 16384
    int i = id >> 7, j = id & 127;
    float dot = 0.f;
    #pragma unroll 8
    for (int h = 0; h < 64; ++h) dot += HG[i * 64 + h] * HG[j * 64 + h];
    float p = 1.f / (1.f + expf(-dot));
    float e = 0.5f * p + 0.5f * A[id];
    float gmb = -logf(-logf(U[id]));
    float arg = (logf(e) - logf(1.f - e) + gmb) * 10.0f;
    out[AAUG_OFF + id] = 1.f / (1.f + expf(-arg));
}

extern "C" void kernel_launch(void* const* d_in, const int* in_sizes, int n_in,
                              void* d_out, int out_size, void* d_ws, size_t ws_size,
                              hipStream_t stream) {
    const float* z  = (const float*)d_in[0];
    const float* LF = (const float*)d_in[1];
    const float* U  = (const float*)d_in[2];
    const float* Wg = (const float*)d_in[3];
    const float* bg = (const float*)d_in[4];
    float* out = (float*)d_out;
    float* W = (float*)d_ws;

    float* AF  = W + OFF_AF;
    ushort_t* Abf = (ushort_t*)(W + OFF_ABF);
    ushort_t* Bbf = (ushort_t*)(W + OFF_BBF);
    ushort_t* Ybf = (ushort_t*)(W + OFF_YBF);
    float* Pg  = W + OFF_PG;
    float* Pm1 = W + OFF_PM1;
    float* A   = W + OFF_A;
    float* X   = W + OFF_X;
    float* HG  = W + OFF_HG;

    k_front<<<5120, 256, 0, stream>>>(LF, z, Pm1, Ybf, Bbf);
    k_m1red<<<256, 256, 0, stream>>>(Pm1, AF, Abf);
    k_m2   <<<1026, 256, 0, stream>>>(AF, Abf);
    k_back <<<1600, 256, 0, stream>>>(Abf, Bbf, Ybf, out, Pg);
    k_plvx <<<64, 256, 0, stream>>>(Pg, z, A, X);
    k_axhg <<<64, 256, 0, stream>>>(A, X, Wg, bg, HG);
    k_aaug <<<64, 256, 0, stream>>>(HG, A, U, out);
}